// Round 12
// baseline (252.007 us; speedup 1.0000x reference)
//
#include <hip/hip_runtime.h>
#include <stdint.h>

typedef short bf16x4 __attribute__((ext_vector_type(4)));
typedef short bf16x8 __attribute__((ext_vector_type(8)));
typedef _Float16 f16x4 __attribute__((ext_vector_type(4)));
typedef _Float16 f16x8 __attribute__((ext_vector_type(8)));
typedef float f32x4 __attribute__((ext_vector_type(4)));
typedef float f32x16 __attribute__((ext_vector_type(16)));
typedef unsigned int u32x4 __attribute__((ext_vector_type(4)));
typedef unsigned int u32x2 __attribute__((ext_vector_type(2)));

#if __has_builtin(__builtin_amdgcn_exp2f)
#define EXP2 __builtin_amdgcn_exp2f
#else
#define EXP2 exp2f
#endif

// ---------- helpers ----------
__device__ __forceinline__ short f2bf(float f) {  // RNE f32->bf16 (finite inputs)
  union { float f; uint32_t u; } v; v.f = f;
  uint32_t r = (v.u + 0x7fffu + ((v.u >> 16) & 1u)) >> 16;
  return (short)(uint16_t)r;
}

__device__ __forceinline__ unsigned cvtpk_bf16(float lo, float hi) {
  unsigned r;
  asm("v_cvt_pk_bf16_f32 %0, %1, %2" : "=v"(r) : "v"(lo), "v"(hi));
  return r;
}

// v_permlane32_swap_b32 via the BUILTIN (hazard-safe; round-5 verified).
#if __has_builtin(__builtin_amdgcn_permlane32_swap)
__device__ __forceinline__ void plane32_swap(unsigned& a, unsigned& b) {
  u32x2 r = __builtin_amdgcn_permlane32_swap(a, b, false, false);
  a = r[0]; b = r[1];
}
__device__ __forceinline__ float xhalf_max(float x) {
  unsigned xu = __builtin_bit_cast(unsigned, x);
  u32x2 r = __builtin_amdgcn_permlane32_swap(xu, xu, false, false);
  return fmaxf(__builtin_bit_cast(float, r[0]), __builtin_bit_cast(float, r[1]));
}
__device__ __forceinline__ float xhalf_sum(float x) {
  unsigned xu = __builtin_bit_cast(unsigned, x);
  u32x2 r = __builtin_amdgcn_permlane32_swap(xu, xu, false, false);
  return __builtin_bit_cast(float, r[0]) + __builtin_bit_cast(float, r[1]);
}
#else
__device__ __forceinline__ void plane32_swap(unsigned& a, unsigned& b) {
  asm("s_nop 1\n\tv_permlane32_swap_b32 %0, %1" : "+v"(a), "+v"(b));
}
__device__ __forceinline__ float xhalf_max(float x) { return fmaxf(x, __shfl_xor(x, 32, 64)); }
__device__ __forceinline__ float xhalf_sum(float x) { return x + __shfl_xor(x, 32, 64); }
#endif

__device__ __forceinline__ float fmax3(float a, float b, float c) {
  return fmaxf(fmaxf(a, b), c);  // clang fuses to v_max3_f32
}

__device__ __forceinline__ float tmax16(const f32x16& s) {
  float a0 = fmax3(s[0], s[1], s[2]);
  float a1 = fmax3(s[3], s[4], s[5]);
  float a2 = fmax3(s[6], s[7], s[8]);
  float a3 = fmax3(s[9], s[10], s[11]);
  float a4 = fmax3(s[12], s[13], s[14]);
  float b0 = fmax3(a0, a1, s[15]);
  float b1 = fmax3(a2, a3, a4);
  return fmaxf(b0, b1);
}
__device__ __forceinline__ float tsum16(const f32x16& s) {
  float a0 = (s[0] + s[1]) + (s[2] + s[3]);
  float a1 = (s[4] + s[5]) + (s[6] + s[7]);
  float a2 = (s[8] + s[9]) + (s[10] + s[11]);
  float a3 = (s[12] + s[13]) + (s[14] + s[15]);
  return (a0 + a1) + (a2 + a3);
}

__device__ __forceinline__ f32x16 zero16() {
  f32x16 z;
#pragma unroll
  for (int i = 0; i < 16; ++i) z[i] = 0.f;
  return z;
}

__device__ __forceinline__ void gld_lds16(const void* g, void* l) {
  __builtin_amdgcn_global_load_lds(
      (__attribute__((address_space(1))) const void*)g,
      (__attribute__((address_space(3))) void*)l, 16, 0, 0);
}

// ---------- RMSNorm + cast to bf16 ----------
__global__ __launch_bounds__(256) void k_rmsnorm(const float* __restrict__ x,
                                                 const float* __restrict__ wn,
                                                 short* __restrict__ xn) {
  const int row = blockIdx.x;      // 8192 rows
  const int t = threadIdx.x;       // 256 threads, 4 floats each
  const float4 v = reinterpret_cast<const float4*>(x + (size_t)row * 1024)[t];
  float ss = v.x * v.x + v.y * v.y + v.z * v.z + v.w * v.w;
#pragma unroll
  for (int m = 32; m >= 1; m >>= 1) ss += __shfl_xor(ss, m, 64);
  __shared__ float red[4];
  if ((t & 63) == 0) red[t >> 6] = ss;
  __syncthreads();
  const float tot = red[0] + red[1] + red[2] + red[3];
  const float rr = rsqrtf(tot * (1.0f / 1024.0f) + 1e-5f);
  const float4 g = reinterpret_cast<const float4*>(wn)[t];
  bf16x4 o;
  o[0] = f2bf(v.x * rr * g.x);
  o[1] = f2bf(v.y * rr * g.y);
  o[2] = f2bf(v.z * rr * g.z);
  o[3] = f2bf(v.w * rr * g.w);
  reinterpret_cast<bf16x4*>(xn + (size_t)row * 1024)[t] = o;
}

// ---------- casts ----------
__global__ __launch_bounds__(256) void k_cast_bf(const float* __restrict__ in,
                                                 short* __restrict__ out, int n4) {
  int i = blockIdx.x * 256 + threadIdx.x;
  if (i >= n4) return;
  float4 v = reinterpret_cast<const float4*>(in)[i];
  bf16x4 o;
  o[0] = f2bf(v.x); o[1] = f2bf(v.y); o[2] = f2bf(v.z); o[3] = f2bf(v.w);
  reinterpret_cast<bf16x4*>(out)[i] = o;
}

__global__ __launch_bounds__(256) void k_cast_f16(const float* __restrict__ in,
                                                  _Float16* __restrict__ out, int n4) {
  int i = blockIdx.x * 256 + threadIdx.x;
  if (i >= n4) return;
  float4 v = reinterpret_cast<const float4*>(in)[i];
  _Float16 o[4] = {(_Float16)v.x, (_Float16)v.y, (_Float16)v.z, (_Float16)v.w};
  reinterpret_cast<ulong1*>(out)[i] = *reinterpret_cast<ulong1*>(o);
}

// ---------- QKV GEMM (bf16, m97 structure, 128x128xBK32, T1 XCD swizzle) ----------
// Epilogue scatters Q to [BH][S][64] (scaled for exp2-softmax) and K/V
// directly into MFMA-FRAGMENT order so attention loads are lane-linear.
__global__ __launch_bounds__(256) void k_gemm_qkv(const short* __restrict__ A,
                                                  const short* __restrict__ B,
                                                  const float* __restrict__ bias,
                                                  short* __restrict__ qb,
                                                  short* __restrict__ kfrag,
                                                  short* __restrict__ vfrag) {
  __shared__ __align__(16) short As[128 * 32];
  __shared__ __align__(16) short Bs[128 * 32];
  const int t = threadIdx.x;
  // T1: XCD-aware remap (nwg = 24*64 = 1536, 1536%8==0)
  const int orig = blockIdx.y * 24 + blockIdx.x;
  const int swz = (orig & 7) * 192 + (orig >> 3);
  const long bn0 = (long)(swz % 24) * 128;
  const long bm0 = (long)(swz / 24) * 128;
  const int w = t >> 6, l = t & 63;
  const int wr = (w >> 1) * 64, wc = (w & 1) * 64;
  const int lm = l & 15, h = l >> 4;
  f32x4 acc[4][4];
#pragma unroll
  for (int i = 0; i < 4; ++i)
#pragma unroll
    for (int j = 0; j < 4; ++j) acc[i][j] = (f32x4){0.f, 0.f, 0.f, 0.f};
  const int srow = t >> 2, scol = (t & 3) * 8;
  const short* Ag = A + (bm0 + srow) * 1024 + scol;
  const short* Bg = B + (bn0 + srow) * 1024 + scol;
  short* AsP = As + t * 8;
  short* BsP = Bs + t * 8;
  for (int kt = 0; kt < 32; ++kt) {
    const int k0 = kt << 5;
    gld_lds16(Ag + k0, AsP);
    gld_lds16(Ag + k0 + 64 * 1024, AsP + 2048);
    gld_lds16(Bg + k0, BsP);
    gld_lds16(Bg + k0 + 64 * 1024, BsP + 2048);
    __syncthreads();
    bf16x8 af[4], bfr[4];
#pragma unroll
    for (int mi = 0; mi < 4; ++mi)
      af[mi] = *reinterpret_cast<const bf16x8*>(As + (wr + mi * 16 + lm) * 32 + h * 8);
#pragma unroll
    for (int ni = 0; ni < 4; ++ni)
      bfr[ni] = *reinterpret_cast<const bf16x8*>(Bs + (wc + ni * 16 + lm) * 32 + h * 8);
    __builtin_amdgcn_s_setprio(1);
#pragma unroll
    for (int mi = 0; mi < 4; ++mi)
#pragma unroll
      for (int ni = 0; ni < 4; ++ni)
        acc[mi][ni] = __builtin_amdgcn_mfma_f32_16x16x32_bf16(af[mi], bfr[ni], acc[mi][ni], 0, 0, 0);
    __builtin_amdgcn_s_setprio(0);
    __syncthreads();
  }
#pragma unroll
  for (int ni = 0; ni < 4; ++ni) {
    const int ncol = (int)bn0 + wc + ni * 16 + lm;
    const float bv = bias[ncol];
    const int which = ncol >> 10;
    const int e = ncol & 1023;
    const int hd = e >> 6, d = e & 63;
#pragma unroll
    for (int mi = 0; mi < 4; ++mi) {
#pragma unroll
      for (int r = 0; r < 4; ++r) {
        const long mrow = bm0 + wr + mi * 16 + h * 4 + r;
        const float val = acc[mi][ni][r] + bv;
        const long bh = (mrow >> 11) * 16 + hd;
        const int seq = (int)(mrow & 2047);
        if (which == 0) {
          const long off = (bh * 2048 + seq) * 64 + d;
          qb[off] = f2bf(val * 0.18033688011112042f);  // 0.125*log2(e)
        } else if (which == 1) {
          const long off = ((bh * 64 + (seq >> 5)) * 4 + (d >> 4)) * 512 +
                           ((seq & 31) | (((d >> 3) & 1) << 5)) * 8 + (d & 7);
          kfrag[off] = f2bf(val);
        } else {
          const long off = (((bh * 64 + (seq >> 5)) * 2 + (d >> 5)) * 2 +
                            ((seq >> 4) & 1)) * 512 +
                           ((d & 31) | (((seq >> 3) & 1) << 5)) * 8 + (seq & 7);
          vfrag[off] = f2bf(val);
        }
      }
    }
  }
}

// ---------- out-proj GEMM (fp16 inputs for precision, fp32 out) ----------
__global__ __launch_bounds__(256) void k_gemm_out(const _Float16* __restrict__ A,
                                                  const _Float16* __restrict__ B,
                                                  const float* __restrict__ bias,
                                                  float* __restrict__ outp) {
  __shared__ __align__(16) _Float16 As[128 * 32];
  __shared__ __align__(16) _Float16 Bs[128 * 32];
  const int t = threadIdx.x;
  // T1: nwg = 8*64 = 512, 512%8==0
  const int orig = blockIdx.y * 8 + blockIdx.x;
  const int swz = (orig & 7) * 64 + (orig >> 3);
  const long bn0 = (long)(swz % 8) * 128;
  const long bm0 = (long)(swz / 8) * 128;
  const int w = t >> 6, l = t & 63;
  const int wr = (w >> 1) * 64, wc = (w & 1) * 64;
  const int lm = l & 15, h = l >> 4;
  f32x4 acc[4][4];
#pragma unroll
  for (int i = 0; i < 4; ++i)
#pragma unroll
    for (int j = 0; j < 4; ++j) acc[i][j] = (f32x4){0.f, 0.f, 0.f, 0.f};
  const int srow = t >> 2, scol = (t & 3) * 8;
  const _Float16* Ag = A + (bm0 + srow) * 1024 + scol;
  const _Float16* Bg = B + (bn0 + srow) * 1024 + scol;
  _Float16* AsP = As + t * 8;
  _Float16* BsP = Bs + t * 8;
  for (int kt = 0; kt < 32; ++kt) {
    const int k0 = kt << 5;
    gld_lds16(Ag + k0, AsP);
    gld_lds16(Ag + k0 + 64 * 1024, AsP + 2048);
    gld_lds16(Bg + k0, BsP);
    gld_lds16(Bg + k0 + 64 * 1024, BsP + 2048);
    __syncthreads();
    f16x8 af[4], bfr[4];
#pragma unroll
    for (int mi = 0; mi < 4; ++mi)
      af[mi] = *reinterpret_cast<const f16x8*>(As + (wr + mi * 16 + lm) * 32 + h * 8);
#pragma unroll
    for (int ni = 0; ni < 4; ++ni)
      bfr[ni] = *reinterpret_cast<const f16x8*>(Bs + (wc + ni * 16 + lm) * 32 + h * 8);
    __builtin_amdgcn_s_setprio(1);
#pragma unroll
    for (int mi = 0; mi < 4; ++mi)
#pragma unroll
      for (int ni = 0; ni < 4; ++ni)
        acc[mi][ni] = __builtin_amdgcn_mfma_f32_16x16x32_f16(af[mi], bfr[ni], acc[mi][ni], 0, 0, 0);
    __builtin_amdgcn_s_setprio(0);
    __syncthreads();
  }
#pragma unroll
  for (int ni = 0; ni < 4; ++ni) {
    const int ncol = (int)bn0 + wc + ni * 16 + lm;
    const float bv = bias[ncol];
#pragma unroll
    for (int mi = 0; mi < 4; ++mi) {
#pragma unroll
      for (int r = 0; r < 4; ++r) {
        const long mrow = bm0 + wr + mi * 16 + h * 4 + r;
        outp[mrow * 1024 + ncol] = acc[mi][ni][r] + bv;
      }
    }
  }
}

// ---------- flash attention v10: split-K=2, LDS-free, reg ping-pong ----------
// Round-11 limiter: grid-capped at 2 waves/SIMD -- serial softmax chain
// exposed. Split-K: 1024 blocks (64 heads x 8 qt x 2 key-halves), each block
// does 32 of the 64 key-tiles for its 256 q-rows. SAME total fragment
// traffic, 1.5x waves/CU (12 vs 8 at VGPR~152). Each half writes
// po = o/l_half (f16, bounded ~max|v|) + per-row (m_half, l_half) stats;
// k_merge combines. Compute core/ping-pong identical to round-11 (verified).
__global__ __launch_bounds__(256) void k_attn(const short* __restrict__ q,
                                              const short* __restrict__ kfrag,
                                              const short* __restrict__ vfrag,
                                              _Float16* __restrict__ po0,
                                              _Float16* __restrict__ po1,
                                              float* __restrict__ stats) {
  // XCD swizzle: 1024 blocks = 8 x 128; each XCD owns 8 whole heads
  const int orig = blockIdx.y * 16 + blockIdx.x;
  const int work = (orig & 7) * 128 + (orig >> 3);
  const int bh = work >> 4;        // 64 heads
  const int qt = (work >> 1) & 7;  // 8 q-tiles of 256 rows
  const int half = work & 1;       // key-range half
  const int t = threadIdx.x;
  const int w = t >> 6, l = t & 63;
  const int lq = l & 31, hh = l >> 5;
  const int qbase = qt * 256 + w * 64;

  // Q fragments: qf[qh][db] = Q[qbase+qh*32+lq][db*16 + hh*8 .. +8]
  bf16x8 qf[2][4];
#pragma unroll
  for (int qh = 0; qh < 2; ++qh) {
    const short* qp = q + ((size_t)(bh * 2048 + qbase + qh * 32 + lq)) * 64 + hh * 8;
#pragma unroll
    for (int db = 0; db < 4; ++db)
      qf[qh][db] = *reinterpret_cast<const bf16x8*>(qp + db * 16);
  }

  // fragment-ordered K/V bases (lane-linear: + l*8 shorts; tile = 2048 shorts)
  const short* kfb = kfrag + (size_t)bh * 64 * 2048 + l * 8;
  const short* vfb = vfrag + (size_t)bh * 64 * 2048 + l * 8;

  f32x16 oa00 = zero16(), oa01 = zero16();  // qh=0: dt=0,1
  f32x16 oa10 = zero16(), oa11 = zero16();  // qh=1: dt=0,1
  float mr0 = -1e30f, mr1 = -1e30f, lr0 = 0.f, lr1 = 0.f;

  auto LOAD = [&](bf16x8* kf, bf16x8* vf, int kt) {
    const short* kp = kfb + (size_t)kt * 2048;
#pragma unroll
    for (int db = 0; db < 4; ++db)
      kf[db] = *reinterpret_cast<const bf16x8*>(kp + db * 512);
    const short* vp = vfb + (size_t)kt * 2048;
#pragma unroll
    for (int i = 0; i < 4; ++i)
      vf[i] = *reinterpret_cast<const bf16x8*>(vp + i * 512);
  };

  auto COMPUTE = [&](const bf16x8* kf, const bf16x8* vf) {
    f32x16 s0 = zero16(), s1 = zero16();  // qh=0, qh=1 (32 keys x 32 q each)
    __builtin_amdgcn_s_setprio(1);
#pragma unroll
    for (int db = 0; db < 4; ++db) {
      s0 = __builtin_amdgcn_mfma_f32_32x32x16_bf16(kf[db], qf[0][db], s0, 0, 0, 0);
      s1 = __builtin_amdgcn_mfma_f32_32x32x16_bf16(kf[db], qf[1][db], s1, 0, 0, 0);
    }
    __builtin_amdgcn_s_setprio(0);
    float tm0 = xhalf_max(tmax16(s0));
    float tm1 = xhalf_max(tmax16(s1));
    // defer-max rescale (log2 domain, THR=8 => P <= 256)
    if (!__all((tm0 <= mr0 + 8.f) && (tm1 <= mr1 + 8.f))) {
      const float mn0 = fmaxf(mr0, tm0), mn1 = fmaxf(mr1, tm1);
      const float c0 = EXP2(mr0 - mn0), c1 = EXP2(mr1 - mn1);
      lr0 *= c0; lr1 *= c1;
#pragma unroll
      for (int r = 0; r < 16; ++r) {
        oa00[r] *= c0; oa01[r] *= c0;
        oa10[r] *= c1; oa11[r] *= c1;
      }
      mr0 = mn0; mr1 = mn1;
    }
#pragma unroll
    for (int r = 0; r < 16; ++r) {
      s0[r] = EXP2(s0[r] - mr0);
      s1[r] = EXP2(s1[r] - mr1);
    }
    lr0 += tsum16(s0);  // per-half-lane partial; xhalf_sum'd at the end
    lr1 += tsum16(s1);
    __builtin_amdgcn_s_setprio(1);
#pragma unroll
    for (int kg = 0; kg < 2; ++kg) {
      const int b0 = kg * 8;
      unsigned p00 = cvtpk_bf16(s0[b0 + 0], s0[b0 + 1]);
      unsigned p01 = cvtpk_bf16(s0[b0 + 2], s0[b0 + 3]);
      unsigned p02 = cvtpk_bf16(s0[b0 + 4], s0[b0 + 5]);
      unsigned p03 = cvtpk_bf16(s0[b0 + 6], s0[b0 + 7]);
      plane32_swap(p00, p02);
      plane32_swap(p01, p03);
      u32x4 pw0 = {p00, p01, p02, p03};
      bf16x8 pf0 = *reinterpret_cast<bf16x8*>(&pw0);
      unsigned p10 = cvtpk_bf16(s1[b0 + 0], s1[b0 + 1]);
      unsigned p11 = cvtpk_bf16(s1[b0 + 2], s1[b0 + 3]);
      unsigned p12 = cvtpk_bf16(s1[b0 + 4], s1[b0 + 5]);
      unsigned p13 = cvtpk_bf16(s1[b0 + 6], s1[b0 + 7]);
      plane32_swap(p10, p12);
      plane32_swap(p11, p13);
      u32x4 pw1 = {p10, p11, p12, p13};
      bf16x8 pf1 = *reinterpret_cast<bf16x8*>(&pw1);
      oa00 = __builtin_amdgcn_mfma_f32_32x32x16_bf16(vf[0 * 2 + kg], pf0, oa00, 0, 0, 0);
      oa10 = __builtin_amdgcn_mfma_f32_32x32x16_bf16(vf[0 * 2 + kg], pf1, oa10, 0, 0, 0);
      oa01 = __builtin_amdgcn_mfma_f32_32x32x16_bf16(vf[1 * 2 + kg], pf0, oa01, 0, 0, 0);
      oa11 = __builtin_amdgcn_mfma_f32_32x32x16_bf16(vf[1 * 2 + kg], pf1, oa11, 0, 0, 0);
    }
    __builtin_amdgcn_s_setprio(0);
  };

  bf16x8 kfA[4], vfA[4], kfB[4], vfB[4];
  const int kt0 = half * 32, kt1 = kt0 + 32;
  LOAD(kfA, vfA, kt0);
  for (int kt = kt0; kt < kt1; kt += 2) {
    LOAD(kfB, vfB, kt + 1);        // kt+1 <= kt1-1 always
    COMPUTE(kfA, vfA);             // waits only kfA/vfA (counted vmcnt)
    int k2 = kt + 2; if (k2 >= kt1) k2 = kt1 - 1;  // junk reload at tail
    LOAD(kfA, vfA, k2);
    COMPUTE(kfB, vfB);
  }
  const float lt0 = xhalf_sum(lr0);
  const float lt1 = xhalf_sum(lr1);
  const float inv0 = 1.0f / lt0;
  const float inv1 = 1.0f / lt1;
  const int b = bh >> 4, hd = bh & 15;
  _Float16* po = half ? po1 : po0;
  _Float16* ob0 = po + ((size_t)(b * 2048 + qbase + lq)) * 1024 + hd * 64;
  _Float16* ob1 = ob0 + 32 * 1024;
#pragma unroll
  for (int r2 = 0; r2 < 16; ++r2) {
    const int d0 = (r2 & 3) + 8 * (r2 >> 2) + 4 * hh;  // 32x32 C layout
    ob0[d0] = (_Float16)(oa00[r2] * inv0);
    ob0[d0 + 32] = (_Float16)(oa01[r2] * inv0);
    ob1[d0] = (_Float16)(oa10[r2] * inv1);
    ob1[d0 + 32] = (_Float16)(oa11[r2] * inv1);
  }
  // per-q-row stats (mr/lt identical in lane pairs l, l^32 -> write from hh==0)
  if (hh == 0) {
    float* st = stats + (size_t)half * 262144;
    const size_t si = (size_t)bh * 2048 + qbase + lq;
    st[si] = mr0;
    st[131072 + si] = lt0;
    st[si + 32] = mr1;
    st[131072 + si + 32] = lt1;
  }
}

// ---------- split-K merge: po0 = combine(po0, po1), in place ----------
__global__ __launch_bounds__(256) void k_merge(_Float16* __restrict__ po0,
                                               const _Float16* __restrict__ po1,
                                               const float* __restrict__ stats) {
  const int row = blockIdx.x;   // 8192 = b*2048 + s
  const int t = threadIdx.x;    // 256 threads x 4 f16
  const int col = t * 4;
  const int hd = col >> 6;
  const int b = row >> 11, s = row & 2047;
  const size_t si = (size_t)(b * 16 + hd) * 2048 + s;
  const float m0 = stats[si], l0 = stats[131072 + si];
  const float m1 = stats[262144 + si], l1 = stats[393216 + si];
  const float mm = fmaxf(m0, m1);
  const float w0 = l0 * EXP2(m0 - mm), w1 = l1 * EXP2(m1 - mm);
  const float inv = 1.0f / (w0 + w1);
  const float a0 = w0 * inv, a1 = w1 * inv;
  const size_t off = (size_t)row * 1024 + col;
  f16x4 v0 = *reinterpret_cast<const f16x4*>(po0 + off);
  f16x4 v1 = *reinterpret_cast<const f16x4*>(po1 + off);
  f16x4 r;
#pragma unroll
  for (int j = 0; j < 4; ++j)
    r[j] = (_Float16)(a0 * (float)v0[j] + a1 * (float)v1[j]);
  *reinterpret_cast<f16x4*>(po0 + off) = r;
}

// ---------- launch ----------
extern "C" void kernel_launch(void* const* d_in, const int* in_sizes, int n_in,
                              void* d_out, int out_size, void* d_ws, size_t ws_size,
                              hipStream_t stream) {
  const float* x = (const float*)d_in[0];
  const float* w_in = (const float*)d_in[1];
  const float* b_in = (const float*)d_in[2];
  const float* w_norm = (const float*)d_in[3];
  const float* w_out = (const float*)d_in[4];
  const float* b_out = (const float*)d_in[5];
  float* out = (float*)d_out;
  char* ws = (char*)d_ws;
  // workspace (91.5 MB total; regions reused across phases):
  short* xn = (short*)(ws);                       // 16 MB; dead after qkv gemm
  _Float16* po1 = (_Float16*)(ws);                //   ... then split-K partial 1
  short* win_b = (short*)(ws + 16777216);         // 6 MB; dead after qkv gemm
  float* stats = (float*)(ws + 16777216);         //   ... then 2 MB m/l stats
  _Float16* wout_h = (_Float16*)(ws + 23068672);  // 2 MB  [1024][1024] f16
  short* qb = (short*)(ws + 25165824);            // 16 MB [BH][S][64] bf16
  short* kfrag = (short*)(ws + 41943040);         // 16 MB fragment-ordered K
  short* vfrag = (short*)(ws + 58720256);         // 16 MB fragment-ordered V
  _Float16* po0 = (_Float16*)(ws + 75497472);     // 16 MB partial 0 / merged o

  k_cast_bf<<<3072, 256, 0, stream>>>(w_in, win_b, 786432);
  k_cast_f16<<<1024, 256, 0, stream>>>(w_out, wout_h, 262144);
  k_rmsnorm<<<8192, 256, 0, stream>>>(x, w_norm, xn);
  k_gemm_qkv<<<dim3(24, 64), 256, 0, stream>>>(xn, win_b, b_in, qb, kfrag, vfrag);
  k_attn<<<dim3(16, 64), 256, 0, stream>>>(qb, kfrag, vfrag, po0, po1, stats);
  k_merge<<<8192, 256, 0, stream>>>(po0, po1, stats);
  k_gemm_out<<<dim3(8, 64), 256, 0, stream>>>(po0, wout_h, b_out, out);
}

// Round 13
// 226.771 us; speedup vs baseline: 1.1113x; 1.1113x over previous
//
#include <hip/hip_runtime.h>
#include <stdint.h>

typedef short bf16x4 __attribute__((ext_vector_type(4)));
typedef short bf16x8 __attribute__((ext_vector_type(8)));
typedef _Float16 f16x8 __attribute__((ext_vector_type(8)));
typedef float f32x4 __attribute__((ext_vector_type(4)));
typedef float f32x16 __attribute__((ext_vector_type(16)));
typedef unsigned int u32x4 __attribute__((ext_vector_type(4)));
typedef unsigned int u32x2 __attribute__((ext_vector_type(2)));

#if __has_builtin(__builtin_amdgcn_exp2f)
#define EXP2 __builtin_amdgcn_exp2f
#else
#define EXP2 exp2f
#endif

// ---------- helpers ----------
__device__ __forceinline__ short f2bf(float f) {  // RNE f32->bf16 (finite inputs)
  union { float f; uint32_t u; } v; v.f = f;
  uint32_t r = (v.u + 0x7fffu + ((v.u >> 16) & 1u)) >> 16;
  return (short)(uint16_t)r;
}

__device__ __forceinline__ unsigned cvtpk_bf16(float lo, float hi) {
  unsigned r;
  asm("v_cvt_pk_bf16_f32 %0, %1, %2" : "=v"(r) : "v"(lo), "v"(hi));
  return r;
}

// v_permlane32_swap_b32 via the BUILTIN (hazard-safe; round-5 verified).
#if __has_builtin(__builtin_amdgcn_permlane32_swap)
__device__ __forceinline__ void plane32_swap(unsigned& a, unsigned& b) {
  u32x2 r = __builtin_amdgcn_permlane32_swap(a, b, false, false);
  a = r[0]; b = r[1];
}
__device__ __forceinline__ float xhalf_max(float x) {
  unsigned xu = __builtin_bit_cast(unsigned, x);
  u32x2 r = __builtin_amdgcn_permlane32_swap(xu, xu, false, false);
  return fmaxf(__builtin_bit_cast(float, r[0]), __builtin_bit_cast(float, r[1]));
}
__device__ __forceinline__ float xhalf_sum(float x) {
  unsigned xu = __builtin_bit_cast(unsigned, x);
  u32x2 r = __builtin_amdgcn_permlane32_swap(xu, xu, false, false);
  return __builtin_bit_cast(float, r[0]) + __builtin_bit_cast(float, r[1]);
}
#else
__device__ __forceinline__ void plane32_swap(unsigned& a, unsigned& b) {
  asm("s_nop 1\n\tv_permlane32_swap_b32 %0, %1" : "+v"(a), "+v"(b));
}
__device__ __forceinline__ float xhalf_max(float x) { return fmaxf(x, __shfl_xor(x, 32, 64)); }
__device__ __forceinline__ float xhalf_sum(float x) { return x + __shfl_xor(x, 32, 64); }
#endif

__device__ __forceinline__ float fmax3(float a, float b, float c) {
  return fmaxf(fmaxf(a, b), c);  // clang fuses to v_max3_f32
}

__device__ __forceinline__ float tmax16(const f32x16& s) {
  float a0 = fmax3(s[0], s[1], s[2]);
  float a1 = fmax3(s[3], s[4], s[5]);
  float a2 = fmax3(s[6], s[7], s[8]);
  float a3 = fmax3(s[9], s[10], s[11]);
  float a4 = fmax3(s[12], s[13], s[14]);
  float b0 = fmax3(a0, a1, s[15]);
  float b1 = fmax3(a2, a3, a4);
  return fmaxf(b0, b1);
}
__device__ __forceinline__ float tsum16(const f32x16& s) {
  float a0 = (s[0] + s[1]) + (s[2] + s[3]);
  float a1 = (s[4] + s[5]) + (s[6] + s[7]);
  float a2 = (s[8] + s[9]) + (s[10] + s[11]);
  float a3 = (s[12] + s[13]) + (s[14] + s[15]);
  return (a0 + a1) + (a2 + a3);
}

__device__ __forceinline__ f32x16 zero16() {
  f32x16 z;
#pragma unroll
  for (int i = 0; i < 16; ++i) z[i] = 0.f;
  return z;
}

__device__ __forceinline__ void gld_lds16(const void* g, void* l) {
  __builtin_amdgcn_global_load_lds(
      (__attribute__((address_space(1))) const void*)g,
      (__attribute__((address_space(3))) void*)l, 16, 0, 0);
}

// ---------- RMSNorm + cast to bf16 ----------
__global__ __launch_bounds__(256) void k_rmsnorm(const float* __restrict__ x,
                                                 const float* __restrict__ wn,
                                                 short* __restrict__ xn) {
  const int row = blockIdx.x;      // 8192 rows
  const int t = threadIdx.x;       // 256 threads, 4 floats each
  const float4 v = reinterpret_cast<const float4*>(x + (size_t)row * 1024)[t];
  float ss = v.x * v.x + v.y * v.y + v.z * v.z + v.w * v.w;
#pragma unroll
  for (int m = 32; m >= 1; m >>= 1) ss += __shfl_xor(ss, m, 64);
  __shared__ float red[4];
  if ((t & 63) == 0) red[t >> 6] = ss;
  __syncthreads();
  const float tot = red[0] + red[1] + red[2] + red[3];
  const float rr = rsqrtf(tot * (1.0f / 1024.0f) + 1e-5f);
  const float4 g = reinterpret_cast<const float4*>(wn)[t];
  bf16x4 o;
  o[0] = f2bf(v.x * rr * g.x);
  o[1] = f2bf(v.y * rr * g.y);
  o[2] = f2bf(v.z * rr * g.z);
  o[3] = f2bf(v.w * rr * g.w);
  reinterpret_cast<bf16x4*>(xn + (size_t)row * 1024)[t] = o;
}

// ---------- casts ----------
__global__ __launch_bounds__(256) void k_cast_bf(const float* __restrict__ in,
                                                 short* __restrict__ out, int n4) {
  int i = blockIdx.x * 256 + threadIdx.x;
  if (i >= n4) return;
  float4 v = reinterpret_cast<const float4*>(in)[i];
  bf16x4 o;
  o[0] = f2bf(v.x); o[1] = f2bf(v.y); o[2] = f2bf(v.z); o[3] = f2bf(v.w);
  reinterpret_cast<bf16x4*>(out)[i] = o;
}

__global__ __launch_bounds__(256) void k_cast_f16(const float* __restrict__ in,
                                                  _Float16* __restrict__ out, int n4) {
  int i = blockIdx.x * 256 + threadIdx.x;
  if (i >= n4) return;
  float4 v = reinterpret_cast<const float4*>(in)[i];
  _Float16 o[4] = {(_Float16)v.x, (_Float16)v.y, (_Float16)v.z, (_Float16)v.w};
  reinterpret_cast<ulong1*>(out)[i] = *reinterpret_cast<ulong1*>(o);
}

// ---------- QKV GEMM (bf16, m97 structure, 128x128xBK32, T1 XCD swizzle) ----------
// Epilogue scatters Q to [BH][S][64] (scaled for exp2-softmax) and K/V
// directly into MFMA-FRAGMENT order so attention loads are lane-linear.
__global__ __launch_bounds__(256) void k_gemm_qkv(const short* __restrict__ A,
                                                  const short* __restrict__ B,
                                                  const float* __restrict__ bias,
                                                  short* __restrict__ qb,
                                                  short* __restrict__ kfrag,
                                                  short* __restrict__ vfrag) {
  __shared__ __align__(16) short As[128 * 32];
  __shared__ __align__(16) short Bs[128 * 32];
  const int t = threadIdx.x;
  // T1: XCD-aware remap (nwg = 24*64 = 1536, 1536%8==0)
  const int orig = blockIdx.y * 24 + blockIdx.x;
  const int swz = (orig & 7) * 192 + (orig >> 3);
  const long bn0 = (long)(swz % 24) * 128;
  const long bm0 = (long)(swz / 24) * 128;
  const int w = t >> 6, l = t & 63;
  const int wr = (w >> 1) * 64, wc = (w & 1) * 64;
  const int lm = l & 15, h = l >> 4;
  f32x4 acc[4][4];
#pragma unroll
  for (int i = 0; i < 4; ++i)
#pragma unroll
    for (int j = 0; j < 4; ++j) acc[i][j] = (f32x4){0.f, 0.f, 0.f, 0.f};
  const int srow = t >> 2, scol = (t & 3) * 8;
  const short* Ag = A + (bm0 + srow) * 1024 + scol;
  const short* Bg = B + (bn0 + srow) * 1024 + scol;
  short* AsP = As + t * 8;
  short* BsP = Bs + t * 8;
  for (int kt = 0; kt < 32; ++kt) {
    const int k0 = kt << 5;
    gld_lds16(Ag + k0, AsP);
    gld_lds16(Ag + k0 + 64 * 1024, AsP + 2048);
    gld_lds16(Bg + k0, BsP);
    gld_lds16(Bg + k0 + 64 * 1024, BsP + 2048);
    __syncthreads();
    bf16x8 af[4], bfr[4];
#pragma unroll
    for (int mi = 0; mi < 4; ++mi)
      af[mi] = *reinterpret_cast<const bf16x8*>(As + (wr + mi * 16 + lm) * 32 + h * 8);
#pragma unroll
    for (int ni = 0; ni < 4; ++ni)
      bfr[ni] = *reinterpret_cast<const bf16x8*>(Bs + (wc + ni * 16 + lm) * 32 + h * 8);
    __builtin_amdgcn_s_setprio(1);
#pragma unroll
    for (int mi = 0; mi < 4; ++mi)
#pragma unroll
      for (int ni = 0; ni < 4; ++ni)
        acc[mi][ni] = __builtin_amdgcn_mfma_f32_16x16x32_bf16(af[mi], bfr[ni], acc[mi][ni], 0, 0, 0);
    __builtin_amdgcn_s_setprio(0);
    __syncthreads();
  }
#pragma unroll
  for (int ni = 0; ni < 4; ++ni) {
    const int ncol = (int)bn0 + wc + ni * 16 + lm;
    const float bv = bias[ncol];
    const int which = ncol >> 10;
    const int e = ncol & 1023;
    const int hd = e >> 6, d = e & 63;
#pragma unroll
    for (int mi = 0; mi < 4; ++mi) {
#pragma unroll
      for (int r = 0; r < 4; ++r) {
        const long mrow = bm0 + wr + mi * 16 + h * 4 + r;
        const float val = acc[mi][ni][r] + bv;
        const long bh = (mrow >> 11) * 16 + hd;
        const int seq = (int)(mrow & 2047);
        if (which == 0) {
          const long off = (bh * 2048 + seq) * 64 + d;
          qb[off] = f2bf(val * 0.18033688011112042f);  // 0.125*log2(e)
        } else if (which == 1) {
          const long off = ((bh * 64 + (seq >> 5)) * 4 + (d >> 4)) * 512 +
                           ((seq & 31) | (((d >> 3) & 1) << 5)) * 8 + (d & 7);
          kfrag[off] = f2bf(val);
        } else {
          const long off = (((bh * 64 + (seq >> 5)) * 2 + (d >> 5)) * 2 +
                            ((seq >> 4) & 1)) * 512 +
                           ((d & 31) | (((seq >> 3) & 1) << 5)) * 8 + (seq & 7);
          vfrag[off] = f2bf(val);
        }
      }
    }
  }
}

// ---------- out-proj GEMM (fp16 inputs for precision, fp32 out) ----------
__global__ __launch_bounds__(256) void k_gemm_out(const _Float16* __restrict__ A,
                                                  const _Float16* __restrict__ B,
                                                  const float* __restrict__ bias,
                                                  float* __restrict__ outp) {
  __shared__ __align__(16) _Float16 As[128 * 32];
  __shared__ __align__(16) _Float16 Bs[128 * 32];
  const int t = threadIdx.x;
  // T1: nwg = 8*64 = 512, 512%8==0
  const int orig = blockIdx.y * 8 + blockIdx.x;
  const int swz = (orig & 7) * 64 + (orig >> 3);
  const long bn0 = (long)(swz % 8) * 128;
  const long bm0 = (long)(swz / 8) * 128;
  const int w = t >> 6, l = t & 63;
  const int wr = (w >> 1) * 64, wc = (w & 1) * 64;
  const int lm = l & 15, h = l >> 4;
  f32x4 acc[4][4];
#pragma unroll
  for (int i = 0; i < 4; ++i)
#pragma unroll
    for (int j = 0; j < 4; ++j) acc[i][j] = (f32x4){0.f, 0.f, 0.f, 0.f};
  const int srow = t >> 2, scol = (t & 3) * 8;
  const _Float16* Ag = A + (bm0 + srow) * 1024 + scol;
  const _Float16* Bg = B + (bn0 + srow) * 1024 + scol;
  _Float16* AsP = As + t * 8;
  _Float16* BsP = Bs + t * 8;
  for (int kt = 0; kt < 32; ++kt) {
    const int k0 = kt << 5;
    gld_lds16(Ag + k0, AsP);
    gld_lds16(Ag + k0 + 64 * 1024, AsP + 2048);
    gld_lds16(Bg + k0, BsP);
    gld_lds16(Bg + k0 + 64 * 1024, BsP + 2048);
    __syncthreads();
    f16x8 af[4], bfr[4];
#pragma unroll
    for (int mi = 0; mi < 4; ++mi)
      af[mi] = *reinterpret_cast<const f16x8*>(As + (wr + mi * 16 + lm) * 32 + h * 8);
#pragma unroll
    for (int ni = 0; ni < 4; ++ni)
      bfr[ni] = *reinterpret_cast<const f16x8*>(Bs + (wc + ni * 16 + lm) * 32 + h * 8);
    __builtin_amdgcn_s_setprio(1);
#pragma unroll
    for (int mi = 0; mi < 4; ++mi)
#pragma unroll
      for (int ni = 0; ni < 4; ++ni)
        acc[mi][ni] = __builtin_amdgcn_mfma_f32_16x16x32_f16(af[mi], bfr[ni], acc[mi][ni], 0, 0, 0);
    __builtin_amdgcn_s_setprio(0);
    __syncthreads();
  }
#pragma unroll
  for (int ni = 0; ni < 4; ++ni) {
    const int ncol = (int)bn0 + wc + ni * 16 + lm;
    const float bv = bias[ncol];
#pragma unroll
    for (int mi = 0; mi < 4; ++mi) {
#pragma unroll
      for (int r = 0; r < 4; ++r) {
        const long mrow = bm0 + wr + mi * 16 + h * 4 + r;
        outp[mrow * 1024 + ncol] = acc[mi][ni][r] + bv;
      }
    }
  }
}

// ---------- flash attention v11: 32 q-rows/wave, <=128 VGPR, 4 waves/SIMD ----------
// Round-12 lesson (m69): waves/SIMD quantizes at VGPR 64/128/256 -- at 148-152
// VGPR every occupancy lever was dead (2/SIMD hard cap). v11 sits UNDER the
// 128 cliff: 32 q-rows/wave (oa 32 + qf 16 regs), K ping-pong prefetch
// (kfA/kfB 32 regs), V just-in-time single-buffered (16 regs; issued at the
// top of each half-iter, consumed ~500cy later in PV -> L2 latency covered).
// __launch_bounds__(256,4): VGPR cap 512/4 = 128, sized to the design (round
// 9's failure was a blind 64-cap). Grid 1024 blocks -> 4 blocks/CU -> 4
// waves/SIMD = 2x the latency cover of rounds 10-12. LDS-free, barrier-free.
__global__ __launch_bounds__(256, 4) void k_attn(const short* __restrict__ q,
                                                 const short* __restrict__ kfrag,
                                                 const short* __restrict__ vfrag,
                                                 _Float16* __restrict__ o) {
  // XCD swizzle: 1024 blocks = 8 x 128; each XCD owns 8 whole heads (4MB L2)
  const int orig = blockIdx.y * 16 + blockIdx.x;
  const int work = (orig & 7) * 128 + (orig >> 3);
  const int bh = work >> 4;    // 64 heads
  const int qt = work & 15;    // 16 q-tiles of 128 rows
  const int t = threadIdx.x;
  const int w = t >> 6, l = t & 63;
  const int lq = l & 31, hh = l >> 5;
  const int qrow = qt * 128 + w * 32 + lq;

  // Q fragments: qf[db] = Q[qrow][db*16 + hh*8 .. +8]
  bf16x8 qf[4];
  const short* qp = q + ((size_t)(bh * 2048 + qrow)) * 64 + hh * 8;
#pragma unroll
  for (int db = 0; db < 4; ++db)
    qf[db] = *reinterpret_cast<const bf16x8*>(qp + db * 16);

  // fragment-ordered K/V bases (lane-linear: + l*8 shorts; tile = 2048 shorts)
  const short* kfb = kfrag + (size_t)bh * 64 * 2048 + l * 8;
  const short* vfb = vfrag + (size_t)bh * 64 * 2048 + l * 8;

  f32x16 oa0 = zero16(), oa1 = zero16();  // dt=0,1 (d = lq, 32+lq)
  float mr = -1e30f, lr = 0.f;

  auto LOADK = [&](bf16x8* kf, int kt) {
    const short* kp = kfb + (size_t)kt * 2048;
#pragma unroll
    for (int db = 0; db < 4; ++db)
      kf[db] = *reinterpret_cast<const bf16x8*>(kp + db * 512);
  };
  auto LOADV = [&](bf16x8* vf, int kt) {
    const short* vp = vfb + (size_t)kt * 2048;
#pragma unroll
    for (int i = 0; i < 4; ++i)
      vf[i] = *reinterpret_cast<const bf16x8*>(vp + i * 512);
  };

  auto COMPUTE = [&](const bf16x8* kf, const bf16x8* vf) {
    f32x16 s = zero16();  // 32 keys x 32 q, q-col = lq
    __builtin_amdgcn_s_setprio(1);
#pragma unroll
    for (int db = 0; db < 4; ++db)
      s = __builtin_amdgcn_mfma_f32_32x32x16_bf16(kf[db], qf[db], s, 0, 0, 0);
    __builtin_amdgcn_s_setprio(0);
    float tm = xhalf_max(tmax16(s));
    // defer-max rescale (log2 domain, THR=8 => P <= 256)
    if (!__all(tm <= mr + 8.f)) {
      const float mn = fmaxf(mr, tm);
      const float c = EXP2(mr - mn);
      lr *= c;
#pragma unroll
      for (int r = 0; r < 16; ++r) { oa0[r] *= c; oa1[r] *= c; }
      mr = mn;
    }
#pragma unroll
    for (int r = 0; r < 16; ++r) s[r] = EXP2(s[r] - mr);
    lr += tsum16(s);  // per-half-lane partial; xhalf_sum'd at the end
    __builtin_amdgcn_s_setprio(1);
#pragma unroll
    for (int kg = 0; kg < 2; ++kg) {
      const int b0 = kg * 8;
      unsigned w0 = cvtpk_bf16(s[b0 + 0], s[b0 + 1]);
      unsigned w1 = cvtpk_bf16(s[b0 + 2], s[b0 + 3]);
      unsigned w2 = cvtpk_bf16(s[b0 + 4], s[b0 + 5]);
      unsigned w3 = cvtpk_bf16(s[b0 + 6], s[b0 + 7]);
      plane32_swap(w0, w2);
      plane32_swap(w1, w3);
      u32x4 pw = {w0, w1, w2, w3};
      bf16x8 pf = *reinterpret_cast<bf16x8*>(&pw);
      oa0 = __builtin_amdgcn_mfma_f32_32x32x16_bf16(vf[0 * 2 + kg], pf, oa0, 0, 0, 0);
      oa1 = __builtin_amdgcn_mfma_f32_32x32x16_bf16(vf[1 * 2 + kg], pf, oa1, 0, 0, 0);
    }
    __builtin_amdgcn_s_setprio(0);
  };

  bf16x8 kfA[4], kfB[4], vf[4];
  LOADK(kfA, 0);
  for (int kt = 0; kt < 64; kt += 2) {
    LOADK(kfB, kt + 1);            // K tile kt+1 in flight across COMPUTE(kt)
    LOADV(vf, kt);                 // V tile kt: consumed ~500cy later in PV
    COMPUTE(kfA, vf);
    int k2 = kt + 2; if (k2 > 63) k2 = 63;  // tail: junk reload, never read
    LOADK(kfA, k2);
    LOADV(vf, kt + 1);
    COMPUTE(kfB, vf);
  }
  const float inv = 1.0f / xhalf_sum(lr);
  const int b = bh >> 4, hd = bh & 15;
  _Float16* ob = o + ((size_t)(b * 2048 + qrow)) * 1024 + hd * 64;
#pragma unroll
  for (int r2 = 0; r2 < 16; ++r2) {
    const int d0 = (r2 & 3) + 8 * (r2 >> 2) + 4 * hh;  // 32x32 C layout
    ob[d0] = (_Float16)(oa0[r2] * inv);
    ob[d0 + 32] = (_Float16)(oa1[r2] * inv);
  }
}

// ---------- launch ----------
extern "C" void kernel_launch(void* const* d_in, const int* in_sizes, int n_in,
                              void* d_out, int out_size, void* d_ws, size_t ws_size,
                              hipStream_t stream) {
  const float* x = (const float*)d_in[0];
  const float* w_in = (const float*)d_in[1];
  const float* b_in = (const float*)d_in[2];
  const float* w_norm = (const float*)d_in[3];
  const float* w_out = (const float*)d_in[4];
  const float* b_out = (const float*)d_in[5];
  float* out = (float*)d_out;
  char* ws = (char*)d_ws;
  short* xn = (short*)(ws);                       // 16 MB [8192][1024] bf16
  short* win_b = (short*)(ws + 16777216);         // 6 MB  [3072][1024] bf16
  _Float16* wout_h = (_Float16*)(ws + 23068672);  // 2 MB  [1024][1024] f16
  short* qb = (short*)(ws + 25165824);            // 16 MB [BH][S][64] bf16
  short* kfrag = (short*)(ws + 41943040);         // 16 MB fragment-ordered K
  short* vfrag = (short*)(ws + 58720256);         // 16 MB fragment-ordered V
  _Float16* ob = (_Float16*)(ws + 75497472);      // 16 MB attn out [B][S][1024] f16

  k_cast_bf<<<3072, 256, 0, stream>>>(w_in, win_b, 786432);
  k_cast_f16<<<1024, 256, 0, stream>>>(w_out, wout_h, 262144);
  k_rmsnorm<<<8192, 256, 0, stream>>>(x, w_norm, xn);
  k_gemm_qkv<<<dim3(24, 64), 256, 0, stream>>>(xn, win_b, b_in, qb, kfrag, vfrag);
  k_attn<<<dim3(16, 64), 256, 0, stream>>>(qb, kfrag, vfrag, ob);
  k_gemm_out<<<dim3(8, 64), 256, 0, stream>>>(ob, wout_h, b_out, out);
}